// Round 6
// baseline (48.168 us; speedup 1.0000x reference)
//
#include <hip/hip_runtime.h>

#define NUM_BINS 10
#define GRID1 2048
#define BLOCK 256
#define CHUNK 2048                 // elems per stage chunk (8 KB per array)
#define ITERS 4                    // chunks per block
#define EPB (CHUNK * ITERS)        // 8192 elems per block; 2048*8192 = 16,777,216
// R5: discriminating experiment for the per-CU read wall. R1-R4 all landed at
// 43-51 us (11.6 GB/s/CU read = 95% of the m13 copy bench's per-CU READ rate)
// regardless of per-wave MLP -> suspected per-CU outstanding-line limit on the
// VGPR-return load path. This version streams both arrays through LDS via the
// global_load_lds DMA path instead. If dur stays ~45 us, the wall is the TCP
// line tracker itself -> roofline.
// Packed 8-bit counter fields: 32 elems/thread max -> 128 after 2 butterfly
// rounds; 16-bit fields after full wave reduce hold <= 2048. No overflow.

typedef float f32x4 __attribute__((ext_vector_type(4)));

__device__ __forceinline__ void gld_lds16(const float* g, float* l) {
    // async 16B/lane global->LDS; LDS dest = wave-uniform base + lane*16 (linear).
    __builtin_amdgcn_global_load_lds(
        (const __attribute__((address_space(1))) void*)g,
        (__attribute__((address_space(3))) void*)l, 16, 0, 0);
}

__device__ __forceinline__ void accum_quad(f32x4 r, f32x4 g, int p[5]) {
    #pragma unroll
    for (int j = 0; j < 4; ++j) {
        float rv = r[j];
        float gv = g[j];
        int b = (int)(rv * 10.0f);               // inputs in [0,1)
        b = b > NUM_BINS - 1 ? NUM_BINS - 1 : b;
        int c = (gv > 0.5f) ? b : b + NUM_BINS;  // ano: 0..9, nor: 10..19
        int inc = 1 << ((c & 3) << 3);
        int sel = c >> 2;                        // 0..4
        #pragma unroll
        for (int k = 0; k < 5; ++k)
            p[k] += (sel == k) ? inc : 0;        // cmp + cndmask + add
    }
}

__global__ __launch_bounds__(BLOCK) void hist_ldsdma(
    const float* __restrict__ res,
    const float* __restrict__ gt,
    int* __restrict__ out,   // [20], pre-zeroed
    int n)
{
    __shared__ float sres[CHUNK];
    __shared__ float sgt[CHUNK];

    const int tid  = threadIdx.x;
    const int lane = tid & 63;
    const int wv   = tid >> 6;

    int p[5] = {0, 0, 0, 0, 0};

    if (n == GRID1 * EPB) {
        const size_t eb = (size_t)blockIdx.x * EPB;   // contiguous region per block
        #pragma unroll
        for (int it = 0; it < ITERS; ++it) {
            const float* sr = res + eb + (size_t)it * CHUNK;
            const float* sg = gt  + eb + (size_t)it * CHUNK;
            __syncthreads();   // prev consume done before overwrite (no-op at it=0)
            // Stage 8 KB per array: 2 x 16B DMA ops per thread per array.
            gld_lds16(sr + tid * 4,        &sres[tid * 4]);
            gld_lds16(sr + 1024 + tid * 4, &sres[1024 + tid * 4]);
            gld_lds16(sg + tid * 4,        &sgt[tid * 4]);
            gld_lds16(sg + 1024 + tid * 4, &sgt[1024 + tid * 4]);
            __syncthreads();   // compiler emits s_waitcnt vmcnt(0) before barrier
            // Consume 8 elems per thread from LDS.
            f32x4 r0 = *(const f32x4*)&sres[tid * 8];
            f32x4 r1 = *(const f32x4*)&sres[tid * 8 + 4];
            f32x4 g0 = *(const f32x4*)&sgt[tid * 8];
            f32x4 g1 = *(const f32x4*)&sgt[tid * 8 + 4];
            accum_quad(r0, g0, p);
            accum_quad(r1, g1, p);
        }
    } else {
        // Generic grid-stride fallback, direct loads.
        const f32x4* res4 = (const f32x4*)res;
        const f32x4* gt4  = (const f32x4*)gt;
        const int n4 = n >> 2;
        const int S  = GRID1 * BLOCK;
        for (int i = blockIdx.x * BLOCK + tid; i < n4; i += S)
            accum_quad(res4[i], gt4[i], p);
    }

    // Wave butterfly reduce: 2 rounds on packed 8-bit (fields <= 128)...
    #pragma unroll
    for (int k = 0; k < 5; ++k) {
        p[k] += __shfl_xor(p[k], 1, 64);
        p[k] += __shfl_xor(p[k], 2, 64);
    }
    // ...widen to 16-bit fields (10 regs x 2 halves)...
    int q[10];
    #pragma unroll
    for (int k = 0; k < 5; ++k) {
        q[2 * k]     = p[k] & 0x00FF00FF;          // counters 4k+0 (lo16), 4k+2 (hi16)
        q[2 * k + 1] = (p[k] >> 8) & 0x00FF00FF;   // counters 4k+1 (lo16), 4k+3 (hi16)
    }
    // ...4 more rounds on 16-bit packed (fields <= 2048).
    #pragma unroll
    for (int m = 4; m <= 32; m <<= 1) {
        #pragma unroll
        for (int k = 0; k < 10; ++k)
            q[k] += __shfl_xor(q[k], m, 64);
    }

    __shared__ int part[4][2 * NUM_BINS];
    if (lane == 0) {
        #pragma unroll
        for (int k = 0; k < 5; ++k) {
            part[wv][4 * k + 0] = q[2 * k] & 0xFFFF;
            part[wv][4 * k + 2] = (int)((unsigned)q[2 * k] >> 16);
            part[wv][4 * k + 1] = q[2 * k + 1] & 0xFFFF;
            part[wv][4 * k + 3] = (int)((unsigned)q[2 * k + 1] >> 16);
        }
    }
    __syncthreads();
    // One wave-instruction of global atomics per block (20 lanes, 2 cache lines).
    if (tid < 2 * NUM_BINS) {
        int s = part[0][tid] + part[1][tid] + part[2][tid] + part[3][tid];
        if (s) atomicAdd(&out[tid], s);
    }
}

extern "C" void kernel_launch(void* const* d_in, const int* in_sizes, int n_in,
                              void* d_out, int out_size, void* d_ws, size_t ws_size,
                              hipStream_t stream) {
    const float* res = (const float*)d_in[0];
    const float* gt  = (const float*)d_in[1];
    int* out = (int*)d_out;

    const int n = in_sizes[0];   // 16,777,216

    // Harness poisons d_out with 0xAA; zero it on-stream (capture-safe).
    hipMemsetAsync(d_out, 0, 2 * NUM_BINS * sizeof(int), stream);
    hist_ldsdma<<<GRID1, BLOCK, 0, stream>>>(res, gt, out, n);
}